// Round 1
// baseline (335.090 us; speedup 1.0000x reference)
//
#include <hip/hip_runtime.h>
#include <math.h>

// Problem constants (shapes fixed by setup_inputs)
#define B     4
#define DIM   256
#define NP    128   // nPnt
#define NS    144   // 12*12 unique token_init rows per batch
#define HID   512   // 4*nPnt
#define H_OUT 120
#define W_OUT 160

__device__ __forceinline__ float gelu_exact(float x) {
    return 0.5f * x * (1.0f + erff(x * 0.70710678118654752440f));
}

// ---------------------------------------------------------------------------
// K1: per unique row n (144/batch): q = ti[n]·pt^T / 16 ; nadj = MLP_nr(q)
// 8 rows per block to amortize weight streaming. grid = 4*18 = 72 blocks.
// ---------------------------------------------------------------------------
__global__ __launch_bounds__(256) void k_nadj(
    const float* __restrict__ ti, const float* __restrict__ pt,
    const float* __restrict__ w1, const float* __restrict__ b1,
    const float* __restrict__ w2, const float* __restrict__ b2,
    float* __restrict__ nadj)
{
    const int b  = blockIdx.x / 18;
    const int n0 = (blockIdx.x % 18) * 8;
    const int tid = threadIdx.x;
    __shared__ float xs[8][DIM];
    __shared__ float qs[8][NP];
    __shared__ float hs[8][HID];

    for (int i = tid; i < 8 * DIM; i += 256) {
        int r = i >> 8, d = i & 255;
        xs[r][d] = ti[(b * NS + n0 + r) * DIM + d];
    }
    __syncthreads();

    // q[r][p] = dot(xs[r], pt[b,p]) / 16
    for (int i = tid; i < 8 * NP; i += 256) {
        int r = i >> 7, p = i & 127;
        const float* prow = pt + (b * NP + p) * DIM;
        float a = 0.f;
        for (int d = 0; d < DIM; ++d) a += xs[r][d] * prow[d];
        qs[r][p] = a * 0.0625f;
    }
    __syncthreads();

    // h[r][k] = gelu(b1[k] + q[r]·w1[:,k])
    for (int k = tid; k < HID; k += 256) {
        float a[8];
        float bb = b1[k];
        #pragma unroll
        for (int r = 0; r < 8; ++r) a[r] = bb;
        for (int p = 0; p < NP; ++p) {
            float wv = w1[p * HID + k];
            #pragma unroll
            for (int r = 0; r < 8; ++r) a[r] += qs[r][p] * wv;
        }
        #pragma unroll
        for (int r = 0; r < 8; ++r) hs[r][k] = gelu_exact(a[r]);
    }
    __syncthreads();

    // nadj[r][p] = b2[p] + h[r]·w2[:,p]
    if (tid < NP) {
        const int p = tid;
        float a[8];
        float bb = b2[p];
        #pragma unroll
        for (int r = 0; r < 8; ++r) a[r] = bb;
        for (int k = 0; k < HID; ++k) {
            float wv = w2[k * NP + p];
            #pragma unroll
            for (int r = 0; r < 8; ++r) a[r] += hs[r][k] * wv;
        }
        #pragma unroll
        for (int r = 0; r < 8; ++r) nadj[(b * NS + n0 + r) * NP + p] = a[r];
    }
}

// ---------------------------------------------------------------------------
// K2: u[b,m,p,d]  (m<12: node_w row-pair y=m; m>=12: node_h row-pair x=m-12)
//     u = (2/sqrt(24)) * sum_{j<12} nadj[row_j][p] * ti[row_j][d]
// grid = 4*24 = 96 blocks, 256 threads (one d per thread).
// ---------------------------------------------------------------------------
__global__ __launch_bounds__(256) void k_u(
    const float* __restrict__ nadj, const float* __restrict__ ti,
    float* __restrict__ u)
{
    const int b = blockIdx.x / 24;
    const int m = blockIdx.x % 24;
    const int tid = threadIdx.x;
    __shared__ float as_[12][NP];
    __shared__ float ts_[12][DIM];

    for (int i = tid; i < 12 * NP; i += 256) {
        int j = i >> 7, p = i & 127;
        int n = (m < 12) ? (m * 12 + j) : (j * 12 + (m - 12));
        as_[j][p] = nadj[(b * NS + n) * NP + p];
    }
    for (int i = tid; i < 12 * DIM; i += 256) {
        int j = i >> 8, d = i & 255;
        int n = (m < 12) ? (m * 12 + j) : (j * 12 + (m - 12));
        ts_[j][d] = ti[(b * NS + n) * DIM + d];
    }
    __syncthreads();

    const int d = tid;
    const float c = 0.40824829046386301637f;  // 2/sqrt(24)
    float tv[12];
    #pragma unroll
    for (int j = 0; j < 12; ++j) tv[j] = ts_[j][d];
    for (int p = 0; p < NP; ++p) {
        float a = 0.f;
        #pragma unroll
        for (int j = 0; j < 12; ++j) a += as_[j][p] * tv[j];
        u[((b * 24 + m) * NP + p) * DIM + d] = a * c;
    }
}

// ---------------------------------------------------------------------------
// K3: token_fused[b,p,d] = b2 + sum_k gelu(b1[k] + sum_m u[b,m,p,d]*w1p[m,k])*w2[k]
//     w1p[m,k] = tf_w1[2m,k] + tf_w1[2m+1,k]  (folds the duplicated 48-vector)
// grid = 4*128 = 512 blocks, 256 threads (one d per thread).
// ---------------------------------------------------------------------------
__global__ __launch_bounds__(256) void k_tf(
    const float* __restrict__ u, const float* __restrict__ w1,
    const float* __restrict__ b1, const float* __restrict__ w2,
    const float* __restrict__ b2, float* __restrict__ tf)
{
    const int b = blockIdx.x / NP;
    const int p = blockIdx.x % NP;
    const int tid = threadIdx.x;
    __shared__ float w1p[24][48];
    __shared__ float b1s[48];
    __shared__ float w2s[48];

    if (tid < 48) { b1s[tid] = b1[tid]; w2s[tid] = w2[tid]; }
    for (int i = tid; i < 24 * 48; i += 256) {
        int m = i / 48, k = i - m * 48;
        w1p[m][k] = w1[(2 * m) * 48 + k] + w1[(2 * m + 1) * 48 + k];
    }
    __syncthreads();

    const int d = tid;
    float v[24];
    #pragma unroll
    for (int m = 0; m < 24; ++m) v[m] = u[((b * 24 + m) * NP + p) * DIM + d];

    float acc = b2[0];
    for (int k = 0; k < 48; ++k) {
        float t = b1s[k];
        #pragma unroll
        for (int m = 0; m < 24; ++m) t += v[m] * w1p[m][k];
        acc += gelu_exact(t) * w2s[k];
    }
    tf[(b * NP + p) * DIM + d] = acc;
}

// ---------------------------------------------------------------------------
// K4: per unique row: logits = MLP_na(ti[n]·pt^T/16); attn = softmax(logits);
//     rowout = attn @ token_fused + ti[n]. 8 rows/block, grid = 72.
// ---------------------------------------------------------------------------
__global__ __launch_bounds__(256) void k_attn(
    const float* __restrict__ ti, const float* __restrict__ pt,
    const float* __restrict__ w1, const float* __restrict__ b1,
    const float* __restrict__ w2, const float* __restrict__ b2,
    const float* __restrict__ tf, float* __restrict__ rowout)
{
    const int b  = blockIdx.x / 18;
    const int n0 = (blockIdx.x % 18) * 8;
    const int tid = threadIdx.x;
    __shared__ float xs[8][DIM];
    __shared__ float qs[8][NP];
    __shared__ float hs[8][HID];

    for (int i = tid; i < 8 * DIM; i += 256) {
        int r = i >> 8, d = i & 255;
        xs[r][d] = ti[(b * NS + n0 + r) * DIM + d];
    }
    __syncthreads();

    for (int i = tid; i < 8 * NP; i += 256) {
        int r = i >> 7, p = i & 127;
        const float* prow = pt + (b * NP + p) * DIM;
        float a = 0.f;
        for (int d = 0; d < DIM; ++d) a += xs[r][d] * prow[d];
        qs[r][p] = a * 0.0625f;
    }
    __syncthreads();

    for (int k = tid; k < HID; k += 256) {
        float a[8];
        float bb = b1[k];
        #pragma unroll
        for (int r = 0; r < 8; ++r) a[r] = bb;
        for (int p = 0; p < NP; ++p) {
            float wv = w1[p * HID + k];
            #pragma unroll
            for (int r = 0; r < 8; ++r) a[r] += qs[r][p] * wv;
        }
        #pragma unroll
        for (int r = 0; r < 8; ++r) hs[r][k] = gelu_exact(a[r]);
    }
    __syncthreads();

    // logits back into qs
    if (tid < NP) {
        const int p = tid;
        float a[8];
        float bb = b2[p];
        #pragma unroll
        for (int r = 0; r < 8; ++r) a[r] = bb;
        for (int k = 0; k < HID; ++k) {
            float wv = w2[k * NP + p];
            #pragma unroll
            for (int r = 0; r < 8; ++r) a[r] += hs[r][k] * wv;
        }
        #pragma unroll
        for (int r = 0; r < 8; ++r) qs[r][p] = a[r];
    }
    __syncthreads();

    // softmax over p (serial per row; 8 rows, tiny)
    if (tid < 8) {
        const int r = tid;
        float mx = -1e30f;
        for (int p = 0; p < NP; ++p) mx = fmaxf(mx, qs[r][p]);
        float s = 0.f;
        for (int p = 0; p < NP; ++p) { float e = expf(qs[r][p] - mx); qs[r][p] = e; s += e; }
        float inv = 1.f / s;
        for (int p = 0; p < NP; ++p) qs[r][p] *= inv;
    }
    __syncthreads();

    // rowout[r][d] = xs[r][d] + sum_p attn[r][p] * tf[b,p,d]
    const int d = tid;
    float a[8];
    #pragma unroll
    for (int r = 0; r < 8; ++r) a[r] = xs[r][d];
    for (int p = 0; p < NP; ++p) {
        float tv = tf[(b * NP + p) * DIM + d];
        #pragma unroll
        for (int r = 0; r < 8; ++r) a[r] += qs[r][p] * tv;
    }
    #pragma unroll
    for (int r = 0; r < 8; ++r) rowout[(b * NS + n0 + r) * DIM + d] = a[r];
}

// ---------------------------------------------------------------------------
// K5: broadcast-scatter unique rows to the [B,120,160,256] output (float4).
// out[b,h,w,:] = rowout[b, (h/10)*12 + (3w/40), :]
// ---------------------------------------------------------------------------
__global__ __launch_bounds__(256) void k_scatter(
    const float4* __restrict__ rowout, float4* __restrict__ out)
{
    const int idx = blockIdx.x * 256 + threadIdx.x;  // over B*H*W*64 float4s
    const int d4 = idx & 63;
    const int w  = (idx >> 6) % W_OUT;
    const int rest = idx / (64 * W_OUT);
    const int h = rest % H_OUT;
    const int b = rest / H_OUT;
    const int src = (h / 10) * 12 + (3 * w) / 40;
    out[idx] = rowout[(b * NS + src) * 64 + d4];
}

extern "C" void kernel_launch(void* const* d_in, const int* in_sizes, int n_in,
                              void* d_out, int out_size, void* d_ws, size_t ws_size,
                              hipStream_t stream) {
    (void)in_sizes; (void)n_in; (void)out_size; (void)ws_size;
    const float* token_init  = (const float*)d_in[0];  // [4,12,12,256] == ti [4,144,256]
    const float* point_token = (const float*)d_in[1];  // [4,128,256]
    const float* nr_w1 = (const float*)d_in[2];
    const float* nr_b1 = (const float*)d_in[3];
    const float* nr_w2 = (const float*)d_in[4];
    const float* nr_b2 = (const float*)d_in[5];
    const float* na_w1 = (const float*)d_in[6];
    const float* na_b1 = (const float*)d_in[7];
    const float* na_w2 = (const float*)d_in[8];
    const float* na_b2 = (const float*)d_in[9];
    const float* tf_w1 = (const float*)d_in[10];
    const float* tf_b1 = (const float*)d_in[11];
    const float* tf_w2 = (const float*)d_in[12];
    const float* tf_b2 = (const float*)d_in[13];
    // d_in[14]=height(120), d_in[15]=width(160) — baked into constants.

    float* out = (float*)d_out;
    float* ws  = (float*)d_ws;
    float* nadj   = ws;                       // 4*144*128      =    73,728 f
    float* u      = nadj + B * NS * NP;       // 4*24*128*256   = 3,145,728 f
    float* tf     = u + B * 24 * NP * DIM;    // 4*128*256      =   131,072 f
    float* rowout = tf + B * NP * DIM;        // 4*144*256      =   147,456 f  (~14 MB total)

    k_nadj<<<B * 18, 256, 0, stream>>>(token_init, point_token,
                                       nr_w1, nr_b1, nr_w2, nr_b2, nadj);
    k_u<<<B * 24, 256, 0, stream>>>(nadj, token_init, u);
    k_tf<<<B * NP, 256, 0, stream>>>(u, tf_w1, tf_b1, tf_w2, tf_b2, tf);
    k_attn<<<B * 18, 256, 0, stream>>>(token_init, point_token,
                                       na_w1, na_b1, na_w2, na_b2, tf, rowout);
    k_scatter<<<(B * H_OUT * W_OUT * 64) / 256, 256, 0, stream>>>(
        (const float4*)rowout, (float4*)out);
}

// Round 2
// 210.220 us; speedup vs baseline: 1.5940x; 1.5940x over previous
//
#include <hip/hip_runtime.h>
#include <math.h>

// Problem constants (shapes fixed by setup_inputs)
#define B     4
#define DIM   256
#define NP    128   // nPnt
#define NS    144   // 12*12 unique token_init rows per batch
#define HID   512   // 4*nPnt
#define NROW  576   // B*NS
#define H_OUT 120
#define W_OUT 160

__device__ __forceinline__ float gelu_exact(float x) {
    return 0.5f * x * (1.0f + erff(x * 0.70710678118654752440f));
}

// ---------------------------------------------------------------------------
// K_q: Q[g][p] = dot(ti[g], pt[b,p]) / 16   (shared by both MLPs)
// grid = 288 (2 rows/block), 256 threads: p = t&127, d-half = t>>7.
// ---------------------------------------------------------------------------
__global__ __launch_bounds__(256) void k_q(
    const float* __restrict__ ti, const float* __restrict__ pt,
    float* __restrict__ Q)
{
    const int g0 = blockIdx.x * 2;
    const int b  = g0 / NS;
    const int t  = threadIdx.x;
    __shared__ float4 xs[2][64];
    __shared__ float  qp[2][2][NP];

    for (int i = t; i < 128; i += 256) {
        int r = i >> 6, c = i & 63;
        xs[r][c] = ((const float4*)ti)[(g0 + r) * 64 + c];
    }
    __syncthreads();

    const int p = t & 127, dh = t >> 7;
    const float4* pr = (const float4*)pt + (b * NP + p) * 64 + dh * 32;
    float a0 = 0.f, a1 = 0.f;
    #pragma unroll 8
    for (int i = 0; i < 32; ++i) {
        float4 v  = pr[i];
        float4 x0 = xs[0][dh * 32 + i];
        float4 x1 = xs[1][dh * 32 + i];
        a0 += v.x * x0.x + v.y * x0.y + v.z * x0.z + v.w * x0.w;
        a1 += v.x * x1.x + v.y * x1.y + v.z * x1.z + v.w * x1.w;
    }
    qp[dh][0][p] = a0;
    qp[dh][1][p] = a1;
    __syncthreads();

    const int r = t >> 7;  // reuse thread as (row, p) writer
    Q[(g0 + r) * NP + p] = (qp[0][r][p] + qp[1][r][p]) * 0.0625f;
}

// ---------------------------------------------------------------------------
// K_h: layer-1 of both MLPs.  H[mlp][g][k] = gelu(b1[k] + Q[g]·w1[:,k])
// grid = 2 mlps × 72 row-tiles(8) × 4 col-tiles(128) = 576 blocks.
// thread: k = ct*128 + (t&127); rows rbase = (t>>7)*4 .. +3  (4 outputs).
// ---------------------------------------------------------------------------
__global__ __launch_bounds__(256) void k_h(
    const float* __restrict__ Q,
    const float* __restrict__ nr_w1, const float* __restrict__ nr_b1,
    const float* __restrict__ na_w1, const float* __restrict__ na_b1,
    float* __restrict__ H)
{
    const int mlp = blockIdx.x / 288;
    const int t2  = blockIdx.x % 288;
    const int g0  = (t2 >> 2) * 8;
    const int k   = (t2 & 3) * 128 + (threadIdx.x & 127);
    const int rb  = (threadIdx.x >> 7) * 4;
    const float* __restrict__ w1 = mlp ? na_w1 : nr_w1;
    const float* __restrict__ b1 = mlp ? na_b1 : nr_b1;

    __shared__ float qs[8][NP];
    for (int i = threadIdx.x; i < 8 * NP; i += 256) {
        int r = i >> 7, p = i & 127;
        qs[r][p] = Q[(g0 + r) * NP + p];
    }
    __syncthreads();

    float acc0, acc1, acc2, acc3;
    acc0 = acc1 = acc2 = acc3 = b1[k];
    for (int p = 0; p < NP; ++p) {
        float wv = w1[p * HID + k];
        acc0 += qs[rb + 0][p] * wv;
        acc1 += qs[rb + 1][p] * wv;
        acc2 += qs[rb + 2][p] * wv;
        acc3 += qs[rb + 3][p] * wv;
    }
    float* __restrict__ Hr = H + (size_t)(mlp * NROW + g0 + rb) * HID + k;
    Hr[0 * HID] = gelu_exact(acc0);
    Hr[1 * HID] = gelu_exact(acc1);
    Hr[2 * HID] = gelu_exact(acc2);
    Hr[3 * HID] = gelu_exact(acc3);
}

// ---------------------------------------------------------------------------
// K_l: layer-2 of both MLPs. mlp0 -> nadj;  mlp1 -> softmax -> attn.
// grid = 2 mlps × 288 row-pairs = 576 blocks; thread: p = t&127, r = t>>7.
// ---------------------------------------------------------------------------
__global__ __launch_bounds__(256) void k_l(
    const float* __restrict__ H,
    const float* __restrict__ nr_w2, const float* __restrict__ nr_b2,
    const float* __restrict__ na_w2, const float* __restrict__ na_b2,
    float* __restrict__ nadj, float* __restrict__ attn)
{
    const int mlp = blockIdx.x / 288;
    const int g0  = (blockIdx.x % 288) * 2;
    const int t   = threadIdx.x;
    const int p   = t & 127, r = t >> 7;
    const float* __restrict__ w2 = mlp ? na_w2 : nr_w2;
    const float* __restrict__ b2 = mlp ? na_b2 : nr_b2;

    __shared__ float hs[2][HID];
    for (int i = t; i < 2 * HID; i += 256) {
        int rr = i >> 9, k = i & 511;
        hs[rr][k] = H[(size_t)(mlp * NROW + g0 + rr) * HID + k];
    }
    __syncthreads();

    float a0 = 0.f, a1 = 0.f, a2 = 0.f, a3 = 0.f;
    for (int k = 0; k < HID; k += 4) {
        a0 += hs[r][k + 0] * w2[(k + 0) * NP + p];
        a1 += hs[r][k + 1] * w2[(k + 1) * NP + p];
        a2 += hs[r][k + 2] * w2[(k + 2) * NP + p];
        a3 += hs[r][k + 3] * w2[(k + 3) * NP + p];
    }
    const float logit = b2[p] + (a0 + a1) + (a2 + a3);

    if (mlp == 0) {
        nadj[(g0 + r) * NP + p] = logit;
    } else {
        __shared__ float red[2][NP];
        red[r][p] = logit;
        __syncthreads();
        for (int s = 64; s > 0; s >>= 1) {
            if (p < s) red[r][p] = fmaxf(red[r][p], red[r][p + s]);
            __syncthreads();
        }
        const float mx = red[r][0];
        __syncthreads();
        const float e = expf(logit - mx);
        red[r][p] = e;
        __syncthreads();
        for (int s = 64; s > 0; s >>= 1) {
            if (p < s) red[r][p] += red[r][p + s];
            __syncthreads();
        }
        attn[(g0 + r) * NP + p] = e / red[r][0];
    }
}

// ---------------------------------------------------------------------------
// K_fold: fused (k_u + k_tf).  For (b,p), thread d:
//   v[m][d] = (2/sqrt24) * sum_j nadj[row(m,j),p] * ti[row(m,j),d]  (regs)
//   tf[b,p,d] = b2 + sum_k gelu(b1[k] + sum_m v[m]*w1p[m][k]) * w2[k]
// grid = 4*128 = 512 blocks.
// ---------------------------------------------------------------------------
__global__ __launch_bounds__(256) void k_fold(
    const float* __restrict__ nadj, const float* __restrict__ ti,
    const float* __restrict__ w1, const float* __restrict__ b1,
    const float* __restrict__ w2, const float* __restrict__ b2,
    float* __restrict__ tf)
{
    const int b = blockIdx.x >> 7;
    const int p = blockIdx.x & 127;
    const int t = threadIdx.x;
    __shared__ float an[NS];
    __shared__ float w1p[24][48];
    __shared__ float b1s[48];
    __shared__ float w2s[48];

    if (t < NS) an[t] = nadj[(b * NS + t) * NP + p];
    if (t >= 192 && t < 240) {
        int k = t - 192;
        b1s[k] = b1[k];
        w2s[k] = w2[k];
    }
    for (int i = t; i < 24 * 48; i += 256) {
        int m = i / 48, k = i - m * 48;
        w1p[m][k] = w1[(2 * m) * 48 + k] + w1[(2 * m + 1) * 48 + k];
    }
    __syncthreads();

    const int d = t;
    const float* __restrict__ tb = ti + (size_t)b * NS * DIM + d;
    float v[24];
    #pragma unroll
    for (int m = 0; m < 24; ++m) v[m] = 0.f;
    #pragma unroll
    for (int y = 0; y < 12; ++y) {
        #pragma unroll
        for (int x = 0; x < 12; ++x) {
            const int n = y * 12 + x;
            const float tv = tb[n * DIM];
            const float a  = an[n];
            v[y]      += a * tv;   // node_w: m=y, j=x
            v[12 + x] += a * tv;   // node_h: m=12+x, j=y
        }
    }
    const float c = 0.40824829046386301637f;  // 2/sqrt(24)
    #pragma unroll
    for (int m = 0; m < 24; ++m) v[m] *= c;

    float acc = b2[0];
    for (int k = 0; k < 48; ++k) {
        float tt = b1s[k];
        #pragma unroll
        for (int m = 0; m < 24; ++m) tt += v[m] * w1p[m][k];
        acc += gelu_exact(tt) * w2s[k];
    }
    tf[(size_t)(b * NP + p) * DIM + d] = acc;
}

// ---------------------------------------------------------------------------
// K_final: rowout[g][d] = ti[g][d] + sum_p attn[g][p] * tf[b,p,d]
// grid = 576 blocks (one unique row), 256 threads (one d each).
// ---------------------------------------------------------------------------
__global__ __launch_bounds__(256) void k_final(
    const float* __restrict__ attn, const float* __restrict__ tf,
    const float* __restrict__ ti, float* __restrict__ rowout)
{
    const int g = blockIdx.x;
    const int b = g / NS;
    const int t = threadIdx.x;
    __shared__ float at[NP];
    if (t < NP) at[t] = attn[g * NP + t];
    __syncthreads();

    const int d = t;
    const float* __restrict__ tp = tf + (size_t)b * NP * DIM + d;
    float a0 = 0.f, a1 = 0.f;
    for (int p = 0; p < NP; p += 2) {
        a0 += at[p]     * tp[p * DIM];
        a1 += at[p + 1] * tp[(p + 1) * DIM];
    }
    rowout[(size_t)g * DIM + d] = ti[(size_t)g * DIM + d] + a0 + a1;
}

// ---------------------------------------------------------------------------
// K_scatter: out[b,h,w,:] = rowout[b, (h/10)*12 + (3w/40), :]   (float4)
// ---------------------------------------------------------------------------
__global__ __launch_bounds__(256) void k_scatter(
    const float4* __restrict__ rowout, float4* __restrict__ out)
{
    const int idx = blockIdx.x * 256 + threadIdx.x;  // over B*H*W*64 float4s
    const int d4 = idx & 63;
    const int w  = (idx >> 6) % W_OUT;
    const int rest = idx / (64 * W_OUT);
    const int h = rest % H_OUT;
    const int b = rest / H_OUT;
    const int src = (h / 10) * 12 + (3 * w) / 40;
    out[idx] = rowout[(b * NS + src) * 64 + d4];
}

extern "C" void kernel_launch(void* const* d_in, const int* in_sizes, int n_in,
                              void* d_out, int out_size, void* d_ws, size_t ws_size,
                              hipStream_t stream) {
    (void)in_sizes; (void)n_in; (void)out_size; (void)ws_size;
    const float* token_init  = (const float*)d_in[0];  // [4,144,256]
    const float* point_token = (const float*)d_in[1];  // [4,128,256]
    const float* nr_w1 = (const float*)d_in[2];
    const float* nr_b1 = (const float*)d_in[3];
    const float* nr_w2 = (const float*)d_in[4];
    const float* nr_b2 = (const float*)d_in[5];
    const float* na_w1 = (const float*)d_in[6];
    const float* na_b1 = (const float*)d_in[7];
    const float* na_w2 = (const float*)d_in[8];
    const float* na_b2 = (const float*)d_in[9];
    const float* tf_w1 = (const float*)d_in[10];
    const float* tf_b1 = (const float*)d_in[11];
    const float* tf_w2 = (const float*)d_in[12];
    const float* tf_b2 = (const float*)d_in[13];

    float* out = (float*)d_out;
    float* ws  = (float*)d_ws;
    float* Q      = ws;                        //   73,728 f
    float* H      = Q + NROW * NP;             //  589,824 f (2 MLPs)
    float* nadj   = H + 2 * NROW * HID;        //   73,728 f
    float* attn   = nadj + NROW * NP;          //   73,728 f
    float* tf     = attn + NROW * NP;          //  131,072 f
    float* rowout = tf + B * NP * DIM;         //  147,456 f   (~4.4 MB total)

    k_q<<<NROW / 2, 256, 0, stream>>>(token_init, point_token, Q);
    k_h<<<576, 256, 0, stream>>>(Q, nr_w1, nr_b1, na_w1, na_b1, H);
    k_l<<<576, 256, 0, stream>>>(H, nr_w2, nr_b2, na_w2, na_b2, nadj, attn);
    k_fold<<<B * NP, 256, 0, stream>>>(nadj, token_init,
                                       tf_w1, tf_b1, tf_w2, tf_b2, tf);
    k_final<<<NROW, 256, 0, stream>>>(attn, tf, token_init, rowout);
    k_scatter<<<(B * H_OUT * W_OUT * 64) / 256, 256, 0, stream>>>(
        (const float4*)rowout, (float4*)out);
}

// Round 3
// 176.532 us; speedup vs baseline: 1.8982x; 1.1908x over previous
//
#include <hip/hip_runtime.h>
#include <math.h>

// Problem constants (shapes fixed by setup_inputs)
#define B     4
#define DIM   256
#define NP    128   // nPnt
#define NS    144   // 12*12 unique token_init rows per batch
#define HID   512   // 4*nPnt
#define NROW  576   // B*NS
#define H_OUT 120
#define W_OUT 160

__device__ __forceinline__ float gelu_exact(float x) {
    return 0.5f * x * (1.0f + erff(x * 0.70710678118654752440f));
}

// ---------------------------------------------------------------------------
// K_q: Q[g][p] = dot(ti[g], pt[b,p]) / 16   (shared by both MLPs)
// grid = 288 (2 rows/block), 256 threads: p = t&127, d-half = t>>7.
// ---------------------------------------------------------------------------
__global__ __launch_bounds__(256) void k_q(
    const float* __restrict__ ti, const float* __restrict__ pt,
    float* __restrict__ Q)
{
    const int g0 = blockIdx.x * 2;
    const int b  = g0 / NS;
    const int t  = threadIdx.x;
    __shared__ float4 xs[2][64];
    __shared__ float  qp[2][2][NP];

    for (int i = t; i < 128; i += 256) {
        int r = i >> 6, c = i & 63;
        xs[r][c] = ((const float4*)ti)[(g0 + r) * 64 + c];
    }
    __syncthreads();

    const int p = t & 127, dh = t >> 7;
    const float4* pr = (const float4*)pt + (b * NP + p) * 64 + dh * 32;
    float a0 = 0.f, a1 = 0.f;
    #pragma unroll 8
    for (int i = 0; i < 32; ++i) {
        float4 v  = pr[i];
        float4 x0 = xs[0][dh * 32 + i];
        float4 x1 = xs[1][dh * 32 + i];
        a0 += v.x * x0.x + v.y * x0.y + v.z * x0.z + v.w * x0.w;
        a1 += v.x * x1.x + v.y * x1.y + v.z * x1.z + v.w * x1.w;
    }
    qp[dh][0][p] = a0;
    qp[dh][1][p] = a1;
    __syncthreads();

    const int r = t >> 7;
    Q[(g0 + r) * NP + p] = (qp[0][r][p] + qp[1][r][p]) * 0.0625f;
}

// ---------------------------------------------------------------------------
// K_h: layer-1 of both MLPs.  H[mlp][g][k] = gelu(b1[k] + Q[g]·w1[:,k])
// grid = 2 mlps × 72 row-tiles(8 rows) × 4 col-tiles(128 k) = 576 blocks.
// thread: k-quad kq = t&31 (covers 128 k via float4), row rg = t>>5 (8 rows).
// float4 weight loads + unroll 8 -> many outstanding loads (latency fix).
// ---------------------------------------------------------------------------
__global__ __launch_bounds__(256) void k_h(
    const float* __restrict__ Q,
    const float* __restrict__ nr_w1, const float* __restrict__ nr_b1,
    const float* __restrict__ na_w1, const float* __restrict__ na_b1,
    float* __restrict__ H)
{
    const int mlp = blockIdx.x / 288;
    const int t2  = blockIdx.x % 288;
    const int g0  = (t2 >> 2) * 8;
    const int kbase = (t2 & 3) * 128;
    const int t   = threadIdx.x;
    const float* __restrict__ w1 = mlp ? na_w1 : nr_w1;
    const float* __restrict__ b1 = mlp ? na_b1 : nr_b1;

    __shared__ float qs[8][NP];
    for (int i = t; i < 8 * NP; i += 256) {
        int r = i >> 7, p = i & 127;
        qs[r][p] = Q[(g0 + r) * NP + p];
    }
    __syncthreads();

    const int kq = t & 31;          // k-quad within tile
    const int rg = t >> 5;          // row 0..7
    const int k0 = kbase + kq * 4;

    float4 acc = *(const float4*)(b1 + k0);
    const float* __restrict__ wp = w1 + k0;
    #pragma unroll 8
    for (int p = 0; p < NP; ++p) {
        const float4 w4 = *(const float4*)(wp + p * HID);
        const float  qv = qs[rg][p];
        acc.x += qv * w4.x;
        acc.y += qv * w4.y;
        acc.z += qv * w4.z;
        acc.w += qv * w4.w;
    }
    float4 o;
    o.x = gelu_exact(acc.x);
    o.y = gelu_exact(acc.y);
    o.z = gelu_exact(acc.z);
    o.w = gelu_exact(acc.w);
    *(float4*)(H + (size_t)(mlp * NROW + g0 + rg) * HID + k0) = o;
}

// ---------------------------------------------------------------------------
// K_l: layer-2 of both MLPs. mlp0 -> nadjT[b*NP+p][n];  mlp1 -> softmax attn.
// grid = 2 mlps × 288 row-pairs = 576 blocks.
// thread: p-quad pq = t&31, k-group kg = t>>5 (64 k each); partials in LDS.
// ---------------------------------------------------------------------------
__global__ __launch_bounds__(256) void k_l(
    const float* __restrict__ H,
    const float* __restrict__ nr_w2, const float* __restrict__ nr_b2,
    const float* __restrict__ na_w2, const float* __restrict__ na_b2,
    float* __restrict__ nadjT, float* __restrict__ attn)
{
    const int mlp = blockIdx.x / 288;
    const int g0  = (blockIdx.x % 288) * 2;
    const int b   = g0 / NS;
    const int n0  = g0 % NS;
    const int t   = threadIdx.x;
    const float* __restrict__ w2 = mlp ? na_w2 : nr_w2;
    const float* __restrict__ b2 = mlp ? na_b2 : nr_b2;

    __shared__ float hs[2][HID];
    {
        const int r = t >> 7, q = t & 127;
        ((float4*)hs[r])[q] =
            ((const float4*)H)[(size_t)(mlp * NROW + g0 + r) * 128 + q];
    }
    __syncthreads();

    const int pq = t & 31;     // p-quad
    const int kg = t >> 5;     // k-group 0..7
    const float4* __restrict__ w24 = (const float4*)w2 + pq;

    float4 acc0 = make_float4(0.f, 0.f, 0.f, 0.f);
    float4 acc1 = make_float4(0.f, 0.f, 0.f, 0.f);
    #pragma unroll 8
    for (int i = 0; i < 64; ++i) {
        const int k = kg * 64 + i;
        const float4 w4 = w24[k * 32];
        const float h0 = hs[0][k];
        const float h1 = hs[1][k];
        acc0.x += h0 * w4.x; acc0.y += h0 * w4.y;
        acc0.z += h0 * w4.z; acc0.w += h0 * w4.w;
        acc1.x += h1 * w4.x; acc1.y += h1 * w4.y;
        acc1.z += h1 * w4.z; acc1.w += h1 * w4.w;
    }

    __shared__ float par[16][NP];   // [kg*2+r][p]
    ((float4*)par[kg * 2 + 0])[pq] = acc0;
    ((float4*)par[kg * 2 + 1])[pq] = acc1;
    __syncthreads();

    const int r = t >> 7, p = t & 127;
    float logit = b2[p];
    #pragma unroll
    for (int kg2 = 0; kg2 < 8; ++kg2) logit += par[kg2 * 2 + r][p];

    if (mlp == 0) {
        nadjT[(size_t)(b * NP + p) * NS + n0 + r] = logit;
    } else {
        __shared__ float red[2][NP];
        red[r][p] = logit;
        __syncthreads();
        for (int s = 64; s > 0; s >>= 1) {
            if (p < s) red[r][p] = fmaxf(red[r][p], red[r][p + s]);
            __syncthreads();
        }
        const float mx = red[r][0];
        __syncthreads();
        const float e = expf(logit - mx);
        red[r][p] = e;
        __syncthreads();
        for (int s = 64; s > 0; s >>= 1) {
            if (p < s) red[r][p] += red[r][p + s];
            __syncthreads();
        }
        attn[(g0 + r) * NP + p] = e / red[r][0];
    }
}

// ---------------------------------------------------------------------------
// K_fold: fused (node_w/node_h einsums + tf MLP).  For (b,p), thread d:
//   v[m] = sum over the 12x12 grid (regs, fully unrolled; coalesced ti reads)
//   tf[b,p,d] = b2 + sum_k gelu(b1[k] + sum_m v[m]*w1p[m][k]) * w2[k]
// grid = 4*128 = 512 blocks.
// ---------------------------------------------------------------------------
__global__ __launch_bounds__(256) void k_fold(
    const float* __restrict__ nadjT, const float* __restrict__ ti,
    const float* __restrict__ w1, const float* __restrict__ b1,
    const float* __restrict__ w2, const float* __restrict__ b2,
    float* __restrict__ tf)
{
    const int b = blockIdx.x >> 7;
    const int p = blockIdx.x & 127;
    const int t = threadIdx.x;
    __shared__ float an[NS];
    __shared__ float w1p[24][48];
    __shared__ float b1s[48];
    __shared__ float w2s[48];

    if (t < NS) an[t] = nadjT[(size_t)(b * NP + p) * NS + t];  // coalesced
    if (t >= 192 && t < 240) {
        int k = t - 192;
        b1s[k] = b1[k];
        w2s[k] = w2[k];
    }
    for (int i = t; i < 24 * 48; i += 256) {
        int m = i / 48, k = i - m * 48;
        w1p[m][k] = w1[(2 * m) * 48 + k] + w1[(2 * m + 1) * 48 + k];
    }
    __syncthreads();

    const int d = t;
    const float* __restrict__ tb = ti + (size_t)b * NS * DIM + d;
    float v[24];
    #pragma unroll
    for (int m = 0; m < 24; ++m) v[m] = 0.f;
    #pragma unroll
    for (int y = 0; y < 12; ++y) {
        #pragma unroll
        for (int x = 0; x < 12; ++x) {
            const int n = y * 12 + x;
            const float tv = tb[n * DIM];
            const float a  = an[n];
            v[y]      += a * tv;   // node_w: m=y, j=x
            v[12 + x] += a * tv;   // node_h: m=12+x, j=y
        }
    }
    const float c = 0.40824829046386301637f;  // 2/sqrt(24)
    #pragma unroll
    for (int m = 0; m < 24; ++m) v[m] *= c;

    float acc = b2[0];
    for (int k = 0; k < 48; ++k) {
        float tt = b1s[k];
        #pragma unroll
        for (int m = 0; m < 24; ++m) tt += v[m] * w1p[m][k];
        acc += gelu_exact(tt) * w2s[k];
    }
    tf[(size_t)(b * NP + p) * DIM + d] = acc;
}

// ---------------------------------------------------------------------------
// K_final: row[d] = ti[g][d] + sum_p attn[g][p]*tf[b,p,d], then broadcast-
// scatter the row directly to out[b,h,w,:] for all (h,w) with src==g.
// grid = 576 blocks; thread: d-quad dq = t&63, p/position-group pg = t>>6.
// ---------------------------------------------------------------------------
__global__ __launch_bounds__(256) void k_final(
    const float* __restrict__ attn, const float* __restrict__ tf,
    const float* __restrict__ ti, float4* __restrict__ out)
{
    const int g = blockIdx.x;
    const int b = g / NS;
    const int n = g % NS;
    const int t = threadIdx.x;
    const int dq = t & 63;
    const int pg = t >> 6;

    __shared__ float  at[NP];
    __shared__ float4 par4[4][64];
    __shared__ float4 rowf[64];

    if (t < NP) at[t] = attn[g * NP + t];
    __syncthreads();

    const float4* __restrict__ tp = (const float4*)tf + (size_t)b * NP * 64 + dq;
    float4 acc = make_float4(0.f, 0.f, 0.f, 0.f);
    #pragma unroll 8
    for (int i = 0; i < 32; ++i) {
        const int p = pg * 32 + i;
        const float  a  = at[p];
        const float4 tv = tp[p * 64];
        acc.x += a * tv.x; acc.y += a * tv.y;
        acc.z += a * tv.z; acc.w += a * tv.w;
    }
    par4[pg][dq] = acc;
    __syncthreads();

    if (t < 64) {
        float4 s = par4[0][t];
        const float4 s1 = par4[1][t], s2 = par4[2][t], s3 = par4[3][t];
        const float4 tiv = ((const float4*)ti)[(size_t)g * 64 + t];
        s.x += s1.x + s2.x + s3.x + tiv.x;
        s.y += s1.y + s2.y + s3.y + tiv.y;
        s.z += s1.z + s2.z + s3.z + tiv.z;
        s.w += s1.w + s2.w + s3.w + tiv.w;
        rowf[t] = s;
    }
    __syncthreads();

    // scatter: src(h,w) = (h/10)*12 + (3w)/40 == n  <=>  h in [10y,10y+10),
    // w in [ceil(40x/3), ceil(40(x+1)/3)) where n = y*12+x.
    const int y = n / 12, x = n % 12;
    const int w_lo = (40 * x + 2) / 3;
    const int w_hi = (40 * x + 42) / 3;
    const float4 val = rowf[dq];
    for (int h = 10 * y; h < 10 * y + 10; ++h) {
        float4* orow = out + (size_t)((b * H_OUT + h) * W_OUT) * 64 + dq;
        for (int w = w_lo + pg; w < w_hi; w += 4) {
            orow[w * 64] = val;
        }
    }
}

extern "C" void kernel_launch(void* const* d_in, const int* in_sizes, int n_in,
                              void* d_out, int out_size, void* d_ws, size_t ws_size,
                              hipStream_t stream) {
    (void)in_sizes; (void)n_in; (void)out_size; (void)ws_size;
    const float* token_init  = (const float*)d_in[0];  // [4,144,256]
    const float* point_token = (const float*)d_in[1];  // [4,128,256]
    const float* nr_w1 = (const float*)d_in[2];
    const float* nr_b1 = (const float*)d_in[3];
    const float* nr_w2 = (const float*)d_in[4];
    const float* nr_b2 = (const float*)d_in[5];
    const float* na_w1 = (const float*)d_in[6];
    const float* na_b1 = (const float*)d_in[7];
    const float* na_w2 = (const float*)d_in[8];
    const float* na_b2 = (const float*)d_in[9];
    const float* tf_w1 = (const float*)d_in[10];
    const float* tf_b1 = (const float*)d_in[11];
    const float* tf_w2 = (const float*)d_in[12];
    const float* tf_b2 = (const float*)d_in[13];

    float* out = (float*)d_out;
    float* ws  = (float*)d_ws;
    float* Q      = ws;                        //   73,728 f
    float* H      = Q + NROW * NP;             //  589,824 f (2 MLPs)
    float* nadjT  = H + 2 * NROW * HID;        //   73,728 f  [b*NP+p][n]
    float* attn   = nadjT + NROW * NP;         //   73,728 f
    float* tf     = attn + NROW * NP;          //  131,072 f  (~3.8 MB total)

    k_q<<<NROW / 2, 256, 0, stream>>>(token_init, point_token, Q);
    k_h<<<576, 256, 0, stream>>>(Q, nr_w1, nr_b1, na_w1, na_b1, H);
    k_l<<<576, 256, 0, stream>>>(H, nr_w2, nr_b2, na_w2, na_b2, nadjT, attn);
    k_fold<<<B * NP, 256, 0, stream>>>(nadjT, token_init,
                                       tf_w1, tf_b1, tf_w2, tf_b2, tf);
    k_final<<<NROW, 256, 0, stream>>>(attn, tf, token_init, (float4*)out);
}

// Round 4
// 171.090 us; speedup vs baseline: 1.9586x; 1.0318x over previous
//
#include <hip/hip_runtime.h>
#include <math.h>

// Problem constants (shapes fixed by setup_inputs)
#define B     4
#define DIM   256
#define NP    128   // nPnt
#define NS    144   // 12*12 unique token_init rows per batch
#define HID   512   // 4*nPnt
#define NROW  576   // B*NS
#define H_OUT 120
#define W_OUT 160

__device__ __forceinline__ float gelu_exact(float x) {
    return 0.5f * x * (1.0f + erff(x * 0.70710678118654752440f));
}

// ---------------------------------------------------------------------------
// K_mlp: fused Q -> layer1 -> layer2 (-> softmax) for BOTH MLPs.
// One block = one (mlp, 4-row tile). grid = 2*144 = 288 blocks, 256 threads.
//   Q[r][p]   = dot(ti[g0+r], pt[b,p]) / 16          (LDS)
//   H[r][k]   = gelu(b1[k] + Q[r]·w1[:,k])           (LDS)
//   logit[r][p] = b2[p] + H[r]·w2[:,p]
//   mlp0 -> nadjT[(b*NP+p)*NS + n]   mlp1 -> softmax -> attn[g][p]
// ---------------------------------------------------------------------------
__global__ __launch_bounds__(256) void k_mlp(
    const float* __restrict__ ti, const float* __restrict__ pt,
    const float* __restrict__ nr_w1, const float* __restrict__ nr_b1,
    const float* __restrict__ nr_w2, const float* __restrict__ nr_b2,
    const float* __restrict__ na_w1, const float* __restrict__ na_b1,
    const float* __restrict__ na_w2, const float* __restrict__ na_b2,
    float* __restrict__ nadjT, float* __restrict__ attn)
{
    const int mlp  = blockIdx.x / 144;
    const int tile = blockIdx.x % 144;
    const int g0 = tile * 4;        // 4 consecutive rows, never crosses batch
    const int b  = g0 / NS;
    const int n0 = g0 % NS;
    const int t  = threadIdx.x;

    const float* __restrict__ w1 = mlp ? na_w1 : nr_w1;
    const float* __restrict__ b1 = mlp ? na_b1 : nr_b1;
    const float* __restrict__ w2 = mlp ? na_w2 : nr_w2;
    const float* __restrict__ b2 = mlp ? na_b2 : nr_b2;

    __shared__ float4 xs4[4][64];       //  4 KB  ti rows
    __shared__ float  qs[4][NP];        //  2 KB
    __shared__ float  hs[4][HID];       //  8 KB
    __shared__ float  par[8][4][NP];    // 16 KB  layer-2 partials
    __shared__ float  red[4][NP];       //  2 KB  softmax scratch

    // ---- Stage A: load ti rows, compute Q[4][128] -------------------------
    {
        const int r = t >> 6, c = t & 63;
        xs4[r][c] = ((const float4*)ti)[(size_t)(g0 + r) * 64 + c];
    }
    __syncthreads();

    const int p  = t & 127;
    const int rh = t >> 7;              // this thread covers rows rh and rh+2
    {
        const float4* __restrict__ pr =
            (const float4*)pt + (size_t)(b * NP + p) * 64;
        float a0 = 0.f, a1 = 0.f;
        #pragma unroll 8
        for (int i = 0; i < 64; ++i) {
            const float4 v  = pr[i];
            const float4 x0 = xs4[rh][i];
            const float4 x1 = xs4[rh + 2][i];
            a0 += v.x*x0.x + v.y*x0.y + v.z*x0.z + v.w*x0.w;
            a1 += v.x*x1.x + v.y*x1.y + v.z*x1.z + v.w*x1.w;
        }
        qs[rh][p]     = a0 * 0.0625f;
        qs[rh + 2][p] = a1 * 0.0625f;
    }
    __syncthreads();

    // ---- Stage B: H = gelu(b1 + Q @ w1) -----------------------------------
    {
        const int kq = t & 127;         // k-quad: k0 = kq*4 covers all 512 k
        const int k0 = kq * 4;
        float4 acc0 = *(const float4*)(b1 + k0);
        float4 acc1 = acc0;
        const float* __restrict__ wp = w1 + k0;
        #pragma unroll 8
        for (int pp = 0; pp < NP; ++pp) {
            const float4 w4 = *(const float4*)(wp + (size_t)pp * HID);
            const float q0 = qs[rh][pp];
            const float q1 = qs[rh + 2][pp];
            acc0.x += q0*w4.x; acc0.y += q0*w4.y;
            acc0.z += q0*w4.z; acc0.w += q0*w4.w;
            acc1.x += q1*w4.x; acc1.y += q1*w4.y;
            acc1.z += q1*w4.z; acc1.w += q1*w4.w;
        }
        float4 o0, o1;
        o0.x = gelu_exact(acc0.x); o0.y = gelu_exact(acc0.y);
        o0.z = gelu_exact(acc0.z); o0.w = gelu_exact(acc0.w);
        o1.x = gelu_exact(acc1.x); o1.y = gelu_exact(acc1.y);
        o1.z = gelu_exact(acc1.z); o1.w = gelu_exact(acc1.w);
        ((float4*)hs[rh])[kq]     = o0;
        ((float4*)hs[rh + 2])[kq] = o1;
    }
    __syncthreads();

    // ---- Stage C: logits = b2 + H @ w2 (k split over 8 groups) ------------
    {
        const int pq = t & 31;          // p-quad: p0 = pq*4
        const int p0 = pq * 4;
        const int kg = t >> 5;          // k-group 0..7, 64 k each
        float4 a0 = make_float4(0.f,0.f,0.f,0.f);
        float4 a1 = a0, a2 = a0, a3 = a0;
        const float4* __restrict__ w24 = (const float4*)(w2 + p0);
        #pragma unroll 8
        for (int i = 0; i < 64; ++i) {
            const int k = kg * 64 + i;
            const float4 w4 = w24[(size_t)k * 32];
            const float h0 = hs[0][k], h1 = hs[1][k];
            const float h2 = hs[2][k], h3 = hs[3][k];
            a0.x += h0*w4.x; a0.y += h0*w4.y; a0.z += h0*w4.z; a0.w += h0*w4.w;
            a1.x += h1*w4.x; a1.y += h1*w4.y; a1.z += h1*w4.z; a1.w += h1*w4.w;
            a2.x += h2*w4.x; a2.y += h2*w4.y; a2.z += h2*w4.z; a2.w += h2*w4.w;
            a3.x += h3*w4.x; a3.y += h3*w4.y; a3.z += h3*w4.z; a3.w += h3*w4.w;
        }
        ((float4*)par[kg][0])[pq] = a0;
        ((float4*)par[kg][1])[pq] = a1;
        ((float4*)par[kg][2])[pq] = a2;
        ((float4*)par[kg][3])[pq] = a3;
    }
    __syncthreads();

    // ---- Reduce + emit ----------------------------------------------------
    float lg0 = b2[p], lg1 = lg0;
    #pragma unroll
    for (int kg = 0; kg < 8; ++kg) {
        lg0 += par[kg][rh][p];
        lg1 += par[kg][rh + 2][p];
    }

    if (mlp == 0) {
        float* __restrict__ dst = nadjT + (size_t)(b * NP + p) * NS + n0;
        dst[rh]     = lg0;
        dst[rh + 2] = lg1;
    } else {
        red[rh][p] = lg0; red[rh + 2][p] = lg1;
        __syncthreads();
        for (int s = 64; s > 0; s >>= 1) {
            if (p < s) {
                red[rh][p]     = fmaxf(red[rh][p],     red[rh][p + s]);
                red[rh + 2][p] = fmaxf(red[rh + 2][p], red[rh + 2][p + s]);
            }
            __syncthreads();
        }
        const float m0 = red[rh][0], m1 = red[rh + 2][0];
        __syncthreads();
        const float e0 = expf(lg0 - m0), e1 = expf(lg1 - m1);
        red[rh][p] = e0; red[rh + 2][p] = e1;
        __syncthreads();
        for (int s = 64; s > 0; s >>= 1) {
            if (p < s) {
                red[rh][p]     += red[rh][p + s];
                red[rh + 2][p] += red[rh + 2][p + s];
            }
            __syncthreads();
        }
        attn[(size_t)(g0 + rh) * NP + p]     = e0 / red[rh][0];
        attn[(size_t)(g0 + rh + 2) * NP + p] = e1 / red[rh + 2][0];
    }
}

// ---------------------------------------------------------------------------
// K_fold: fused (node_w/node_h einsums + tf MLP).  For (b,p), thread d:
//   v[m] = sum over the 12x12 grid (regs, fully unrolled; coalesced ti reads)
//   tf[b,p,d] = b2 + sum_k gelu(b1[k] + sum_m v[m]*w1p[m][k]) * w2[k]
// grid = 4*128 = 512 blocks.
// ---------------------------------------------------------------------------
__global__ __launch_bounds__(256) void k_fold(
    const float* __restrict__ nadjT, const float* __restrict__ ti,
    const float* __restrict__ w1, const float* __restrict__ b1,
    const float* __restrict__ w2, const float* __restrict__ b2,
    float* __restrict__ tf)
{
    const int b = blockIdx.x >> 7;
    const int p = blockIdx.x & 127;
    const int t = threadIdx.x;
    __shared__ float an[NS];
    __shared__ float w1p[24][48];
    __shared__ float b1s[48];
    __shared__ float w2s[48];

    if (t < 36) {   // 144 floats = 36 float4, coalesced from nadjT row
        ((float4*)an)[t] =
            ((const float4*)(nadjT + (size_t)(b * NP + p) * NS))[t];
    }
    if (t >= 192 && t < 240) {
        const int k = t - 192;
        b1s[k] = b1[k];
        w2s[k] = w2[k];
    }
    for (int i = t; i < 24 * 48; i += 256) {
        const int m = i / 48, k = i - m * 48;
        w1p[m][k] = w1[(2 * m) * 48 + k] + w1[(2 * m + 1) * 48 + k];
    }
    __syncthreads();

    const int d = t;
    const float* __restrict__ tb = ti + (size_t)b * NS * DIM + d;
    float v[24];
    #pragma unroll
    for (int m = 0; m < 24; ++m) v[m] = 0.f;
    #pragma unroll
    for (int y = 0; y < 12; ++y) {
        #pragma unroll
        for (int x = 0; x < 12; ++x) {
            const int n = y * 12 + x;
            const float tv = tb[n * DIM];
            const float a  = an[n];
            v[y]      += a * tv;   // node_w: m=y, j=x
            v[12 + x] += a * tv;   // node_h: m=12+x, j=y
        }
    }
    const float c = 0.40824829046386301637f;  // 2/sqrt(24)
    #pragma unroll
    for (int m = 0; m < 24; ++m) v[m] *= c;

    float acc = b2[0];
    for (int k = 0; k < 48; ++k) {
        float tt = b1s[k];
        #pragma unroll
        for (int m = 0; m < 24; ++m) tt += v[m] * w1p[m][k];
        acc += gelu_exact(tt) * w2s[k];
    }
    tf[(size_t)(b * NP + p) * DIM + d] = acc;
}

// ---------------------------------------------------------------------------
// K_final: row[d] = ti[g][d] + sum_p attn[g][p]*tf[b,p,d], then broadcast-
// scatter the row directly to out[b,h,w,:] for all (h,w) with src==g.
// grid = 576 blocks; thread: d-quad dq = t&63, p-group pg = t>>6.
// ---------------------------------------------------------------------------
__global__ __launch_bounds__(256) void k_final(
    const float* __restrict__ attn, const float* __restrict__ tf,
    const float* __restrict__ ti, float4* __restrict__ out)
{
    const int g = blockIdx.x;
    const int b = g / NS;
    const int n = g % NS;
    const int t = threadIdx.x;
    const int dq = t & 63;
    const int pg = t >> 6;

    __shared__ float  at[NP];
    __shared__ float4 par4[4][64];
    __shared__ float4 rowf[64];

    if (t < NP) at[t] = attn[(size_t)g * NP + t];
    __syncthreads();

    const float4* __restrict__ tp = (const float4*)tf + (size_t)b * NP * 64 + dq;
    float4 acc = make_float4(0.f, 0.f, 0.f, 0.f);
    #pragma unroll 8
    for (int i = 0; i < 32; ++i) {
        const int pp = pg * 32 + i;
        const float  a  = at[pp];
        const float4 tv = tp[(size_t)pp * 64];
        acc.x += a * tv.x; acc.y += a * tv.y;
        acc.z += a * tv.z; acc.w += a * tv.w;
    }
    par4[pg][dq] = acc;
    __syncthreads();

    if (t < 64) {
        float4 s = par4[0][t];
        const float4 s1 = par4[1][t], s2 = par4[2][t], s3 = par4[3][t];
        const float4 tiv = ((const float4*)ti)[(size_t)g * 64 + t];
        s.x += s1.x + s2.x + s3.x + tiv.x;
        s.y += s1.y + s2.y + s3.y + tiv.y;
        s.z += s1.z + s2.z + s3.z + tiv.z;
        s.w += s1.w + s2.w + s3.w + tiv.w;
        rowf[t] = s;
    }
    __syncthreads();

    // scatter: src(h,w) = (h/10)*12 + (3w)/40 == n  <=>  h in [10y,10y+10),
    // w in [ceil(40x/3), ceil(40x/3 + 40/3)) where n = y*12+x.
    const int y = n / 12, x = n % 12;
    const int w_lo = (40 * x + 2) / 3;
    const int w_hi = (40 * x + 42) / 3;
    const float4 val = rowf[dq];
    for (int h = 10 * y; h < 10 * y + 10; ++h) {
        float4* __restrict__ orow = out + (size_t)((b * H_OUT + h) * W_OUT) * 64 + dq;
        for (int w = w_lo + pg; w < w_hi; w += 4) {
            orow[(size_t)w * 64] = val;
        }
    }
}

extern "C" void kernel_launch(void* const* d_in, const int* in_sizes, int n_in,
                              void* d_out, int out_size, void* d_ws, size_t ws_size,
                              hipStream_t stream) {
    (void)in_sizes; (void)n_in; (void)out_size; (void)ws_size;
    const float* token_init  = (const float*)d_in[0];  // [4,144,256]
    const float* point_token = (const float*)d_in[1];  // [4,128,256]
    const float* nr_w1 = (const float*)d_in[2];
    const float* nr_b1 = (const float*)d_in[3];
    const float* nr_w2 = (const float*)d_in[4];
    const float* nr_b2 = (const float*)d_in[5];
    const float* na_w1 = (const float*)d_in[6];
    const float* na_b1 = (const float*)d_in[7];
    const float* na_w2 = (const float*)d_in[8];
    const float* na_b2 = (const float*)d_in[9];
    const float* tf_w1 = (const float*)d_in[10];
    const float* tf_b1 = (const float*)d_in[11];
    const float* tf_w2 = (const float*)d_in[12];
    const float* tf_b2 = (const float*)d_in[13];

    float* out = (float*)d_out;
    float* ws  = (float*)d_ws;
    float* nadjT = ws;                  //  73,728 f  [b*NP+p][n]
    float* attn  = nadjT + NROW * NP;   //  73,728 f
    float* tf    = attn + NROW * NP;    // 131,072 f   (~1.1 MB total)

    k_mlp<<<288, 256, 0, stream>>>(token_init, point_token,
                                   nr_w1, nr_b1, nr_w2, nr_b2,
                                   na_w1, na_b1, na_w2, na_b2,
                                   nadjT, attn);
    k_fold<<<B * NP, 256, 0, stream>>>(nadjT, token_init,
                                       tf_w1, tf_b1, tf_w2, tf_b2, tf);
    k_final<<<NROW, 256, 0, stream>>>(attn, tf, token_init, (float4*)out);
}

// Round 5
// 167.436 us; speedup vs baseline: 2.0013x; 1.0218x over previous
//
#include <hip/hip_runtime.h>
#include <math.h>

// Problem constants (shapes fixed by setup_inputs)
#define B     4
#define DIM   256
#define NP    128   // nPnt
#define NS    144   // 12*12 unique token_init rows per batch
#define HID   512   // 4*nPnt
#define NROW  576   // B*NS
#define H_OUT 120
#define W_OUT 160

__device__ __forceinline__ float gelu_exact(float x) {
    return 0.5f * x * (1.0f + erff(x * 0.70710678118654752440f));
}

// ---------------------------------------------------------------------------
// K_t: transpose point_token -> ptT[b][d][p]  (so Q-stage reads are
// lane-coalesced on p). LDS 32x33 tile transpose. grid = 4*8*4 = 128 blocks.
// ---------------------------------------------------------------------------
__global__ __launch_bounds__(256) void k_t(
    const float* __restrict__ pt, float* __restrict__ ptT)
{
    const int bid = blockIdx.x;
    const int b   = bid >> 5;
    const int rem = bid & 31;
    const int d0  = (rem >> 2) * 32;
    const int p0  = (rem & 3) * 32;
    const int t   = threadIdx.x;
    __shared__ float tile[32][33];

    #pragma unroll
    for (int i = t; i < 1024; i += 256) {
        const int row = i >> 5, col = i & 31;        // row = p-local, col = d-local
        tile[row][col] = pt[(size_t)(b * NP + p0 + row) * DIM + d0 + col];
    }
    __syncthreads();
    #pragma unroll
    for (int i = t; i < 1024; i += 256) {
        const int row = i >> 5, col = i & 31;        // row = d-local, col = p-local
        ptT[(size_t)(b * DIM + d0 + row) * NP + p0 + col] = tile[col][row];
    }
}

// ---------------------------------------------------------------------------
// K_mlp: fused Q -> layer1 -> layer2 (-> softmax) for BOTH MLPs.
// One block = one (mlp, 4-row tile). grid = 2*144 = 288 blocks, 256 threads.
// Stage A now reads ptT (coalesced float4 on p).
// ---------------------------------------------------------------------------
__global__ __launch_bounds__(256) void k_mlp(
    const float* __restrict__ ti, const float* __restrict__ ptT,
    const float* __restrict__ nr_w1, const float* __restrict__ nr_b1,
    const float* __restrict__ nr_w2, const float* __restrict__ nr_b2,
    const float* __restrict__ na_w1, const float* __restrict__ na_b1,
    const float* __restrict__ na_w2, const float* __restrict__ na_b2,
    float* __restrict__ nadjT, float* __restrict__ attn)
{
    const int mlp  = blockIdx.x / 144;
    const int tile = blockIdx.x % 144;
    const int g0 = tile * 4;        // 4 consecutive rows, never crosses batch
    const int b  = g0 / NS;
    const int n0 = g0 % NS;
    const int t  = threadIdx.x;

    const float* __restrict__ w1 = mlp ? na_w1 : nr_w1;
    const float* __restrict__ b1 = mlp ? na_b1 : nr_b1;
    const float* __restrict__ w2 = mlp ? na_w2 : nr_w2;
    const float* __restrict__ b2 = mlp ? na_b2 : nr_b2;

    __shared__ float xs[4][DIM];        //  4 KB  ti rows
    __shared__ float parA[2][4][NP];    //  4 KB  Q partials (2 d-halves)
    __shared__ float qs[4][NP];         //  2 KB
    __shared__ float hs[4][HID];        //  8 KB
    __shared__ float par[8][4][NP];     // 16 KB  layer-2 partials
    __shared__ float red[4][NP];        //  2 KB  softmax scratch

    // ---- Stage A: Q[4][128] = ti_rows @ ptT, coalesced ---------------------
    {
        const int r = t >> 6, c = t & 63;
        ((float4*)xs[r])[c] = ((const float4*)ti)[(size_t)(g0 + r) * 64 + c];
    }
    __syncthreads();

    {
        const int pq = t & 31;          // p-quad: p covers pq*4 .. +3
        const int rr = (t >> 5) & 3;    // row
        const int dh = t >> 7;          // d-half
        const float4* __restrict__ pT4 =
            (const float4*)(ptT + (size_t)b * DIM * NP) + pq;
        float4 acc = make_float4(0.f, 0.f, 0.f, 0.f);
        #pragma unroll 8
        for (int d2 = 0; d2 < 128; ++d2) {
            const int d = dh * 128 + d2;
            const float4 v4 = pT4[(size_t)d * 32];
            const float  xv = xs[rr][d];
            acc.x += xv * v4.x; acc.y += xv * v4.y;
            acc.z += xv * v4.z; acc.w += xv * v4.w;
        }
        ((float4*)parA[dh][rr])[pq] = acc;
    }
    __syncthreads();

    const int p  = t & 127;
    const int rh = t >> 7;              // this thread covers rows rh and rh+2
    qs[rh][p]     = (parA[0][rh][p]     + parA[1][rh][p])     * 0.0625f;
    qs[rh + 2][p] = (parA[0][rh + 2][p] + parA[1][rh + 2][p]) * 0.0625f;
    __syncthreads();

    // ---- Stage B: H = gelu(b1 + Q @ w1) -----------------------------------
    {
        const int kq = t & 127;         // k-quad: k0 = kq*4 covers all 512 k
        const int k0 = kq * 4;
        float4 acc0 = *(const float4*)(b1 + k0);
        float4 acc1 = acc0;
        const float* __restrict__ wp = w1 + k0;
        #pragma unroll 8
        for (int pp = 0; pp < NP; ++pp) {
            const float4 w4 = *(const float4*)(wp + (size_t)pp * HID);
            const float q0 = qs[rh][pp];
            const float q1 = qs[rh + 2][pp];
            acc0.x += q0*w4.x; acc0.y += q0*w4.y;
            acc0.z += q0*w4.z; acc0.w += q0*w4.w;
            acc1.x += q1*w4.x; acc1.y += q1*w4.y;
            acc1.z += q1*w4.z; acc1.w += q1*w4.w;
        }
        float4 o0, o1;
        o0.x = gelu_exact(acc0.x); o0.y = gelu_exact(acc0.y);
        o0.z = gelu_exact(acc0.z); o0.w = gelu_exact(acc0.w);
        o1.x = gelu_exact(acc1.x); o1.y = gelu_exact(acc1.y);
        o1.z = gelu_exact(acc1.z); o1.w = gelu_exact(acc1.w);
        ((float4*)hs[rh])[kq]     = o0;
        ((float4*)hs[rh + 2])[kq] = o1;
    }
    __syncthreads();

    // ---- Stage C: logits = b2 + H @ w2 (k split over 8 groups) ------------
    {
        const int pq = t & 31;          // p-quad: p0 = pq*4
        const int p0 = pq * 4;
        const int kg = t >> 5;          // k-group 0..7, 64 k each
        float4 a0 = make_float4(0.f,0.f,0.f,0.f);
        float4 a1 = a0, a2 = a0, a3 = a0;
        const float4* __restrict__ w24 = (const float4*)(w2 + p0);
        #pragma unroll 8
        for (int i = 0; i < 64; ++i) {
            const int k = kg * 64 + i;
            const float4 w4 = w24[(size_t)k * 32];
            const float h0 = hs[0][k], h1 = hs[1][k];
            const float h2 = hs[2][k], h3 = hs[3][k];
            a0.x += h0*w4.x; a0.y += h0*w4.y; a0.z += h0*w4.z; a0.w += h0*w4.w;
            a1.x += h1*w4.x; a1.y += h1*w4.y; a1.z += h1*w4.z; a1.w += h1*w4.w;
            a2.x += h2*w4.x; a2.y += h2*w4.y; a2.z += h2*w4.z; a2.w += h2*w4.w;
            a3.x += h3*w4.x; a3.y += h3*w4.y; a3.z += h3*w4.z; a3.w += h3*w4.w;
        }
        ((float4*)par[kg][0])[pq] = a0;
        ((float4*)par[kg][1])[pq] = a1;
        ((float4*)par[kg][2])[pq] = a2;
        ((float4*)par[kg][3])[pq] = a3;
    }
    __syncthreads();

    // ---- Reduce + emit ----------------------------------------------------
    float lg0 = b2[p], lg1 = lg0;
    #pragma unroll
    for (int kg = 0; kg < 8; ++kg) {
        lg0 += par[kg][rh][p];
        lg1 += par[kg][rh + 2][p];
    }

    if (mlp == 0) {
        float* __restrict__ dst = nadjT + (size_t)(b * NP + p) * NS + n0;
        dst[rh]     = lg0;
        dst[rh + 2] = lg1;
    } else {
        red[rh][p] = lg0; red[rh + 2][p] = lg1;
        __syncthreads();
        for (int s = 64; s > 0; s >>= 1) {
            if (p < s) {
                red[rh][p]     = fmaxf(red[rh][p],     red[rh][p + s]);
                red[rh + 2][p] = fmaxf(red[rh + 2][p], red[rh + 2][p + s]);
            }
            __syncthreads();
        }
        const float m0 = red[rh][0], m1 = red[rh + 2][0];
        __syncthreads();
        const float e0 = expf(lg0 - m0), e1 = expf(lg1 - m1);
        red[rh][p] = e0; red[rh + 2][p] = e1;
        __syncthreads();
        for (int s = 64; s > 0; s >>= 1) {
            if (p < s) {
                red[rh][p]     += red[rh][p + s];
                red[rh + 2][p] += red[rh + 2][p + s];
            }
            __syncthreads();
        }
        attn[(size_t)(g0 + rh) * NP + p]     = e0 / red[rh][0];
        attn[(size_t)(g0 + rh + 2) * NP + p] = e1 / red[rh + 2][0];
    }
}

// ---------------------------------------------------------------------------
// K_fold: fused (node_w/node_h einsums + tf MLP).  For (b,p), thread d:
//   v[m] = sum over the 12x12 grid (regs, fully unrolled; coalesced ti reads)
//   tf[b,p,d] = b2 + sum_k gelu(b1[k] + sum_m v[m]*w1p[m][k]) * w2[k]
// grid = 4*128 = 512 blocks.
// ---------------------------------------------------------------------------
__global__ __launch_bounds__(256) void k_fold(
    const float* __restrict__ nadjT, const float* __restrict__ ti,
    const float* __restrict__ w1, const float* __restrict__ b1,
    const float* __restrict__ w2, const float* __restrict__ b2,
    float* __restrict__ tf)
{
    const int b = blockIdx.x >> 7;
    const int p = blockIdx.x & 127;
    const int t = threadIdx.x;
    __shared__ float an[NS];
    __shared__ float w1p[24][48];
    __shared__ float b1s[48];
    __shared__ float w2s[48];

    if (t < 36) {   // 144 floats = 36 float4, coalesced from nadjT row
        ((float4*)an)[t] =
            ((const float4*)(nadjT + (size_t)(b * NP + p) * NS))[t];
    }
    if (t >= 192 && t < 240) {
        const int k = t - 192;
        b1s[k] = b1[k];
        w2s[k] = w2[k];
    }
    for (int i = t; i < 24 * 48; i += 256) {
        const int m = i / 48, k = i - m * 48;
        w1p[m][k] = w1[(2 * m) * 48 + k] + w1[(2 * m + 1) * 48 + k];
    }
    __syncthreads();

    const int d = t;
    const float* __restrict__ tb = ti + (size_t)b * NS * DIM + d;
    float v[24];
    #pragma unroll
    for (int m = 0; m < 24; ++m) v[m] = 0.f;
    #pragma unroll
    for (int y = 0; y < 12; ++y) {
        #pragma unroll
        for (int x = 0; x < 12; ++x) {
            const int n = y * 12 + x;
            const float tv = tb[n * DIM];
            const float a  = an[n];
            v[y]      += a * tv;   // node_w: m=y, j=x
            v[12 + x] += a * tv;   // node_h: m=12+x, j=y
        }
    }
    const float c = 0.40824829046386301637f;  // 2/sqrt(24)
    #pragma unroll
    for (int m = 0; m < 24; ++m) v[m] *= c;

    float acc = b2[0];
    for (int k = 0; k < 48; ++k) {
        float tt = b1s[k];
        #pragma unroll
        for (int m = 0; m < 24; ++m) tt += v[m] * w1p[m][k];
        acc += gelu_exact(tt) * w2s[k];
    }
    tf[(size_t)(b * NP + p) * DIM + d] = acc;
}

// ---------------------------------------------------------------------------
// K_final: row[d] = ti[g][d] + sum_p attn[g][p]*tf[b,p,d], then broadcast-
// scatter the row to out[b,h,w,:] for its (h,w) set. 2 blocks per row g
// (each takes 5 of the 10 h-lines) for write parallelism. grid = 1152.
// ---------------------------------------------------------------------------
__global__ __launch_bounds__(256) void k_final(
    const float* __restrict__ attn, const float* __restrict__ tf,
    const float* __restrict__ ti, float4* __restrict__ out)
{
    const int g    = blockIdx.x >> 1;
    const int half = blockIdx.x & 1;
    const int b = g / NS;
    const int n = g % NS;
    const int t = threadIdx.x;
    const int dq = t & 63;
    const int pg = t >> 6;

    __shared__ float  at[NP];
    __shared__ float4 par4[4][64];
    __shared__ float4 rowf[64];

    if (t < NP) at[t] = attn[(size_t)g * NP + t];
    __syncthreads();

    const float4* __restrict__ tp = (const float4*)tf + (size_t)b * NP * 64 + dq;
    float4 acc = make_float4(0.f, 0.f, 0.f, 0.f);
    #pragma unroll 8
    for (int i = 0; i < 32; ++i) {
        const int pp = pg * 32 + i;
        const float  a  = at[pp];
        const float4 tv = tp[(size_t)pp * 64];
        acc.x += a * tv.x; acc.y += a * tv.y;
        acc.z += a * tv.z; acc.w += a * tv.w;
    }
    par4[pg][dq] = acc;
    __syncthreads();

    if (t < 64) {
        float4 s = par4[0][t];
        const float4 s1 = par4[1][t], s2 = par4[2][t], s3 = par4[3][t];
        const float4 tiv = ((const float4*)ti)[(size_t)g * 64 + t];
        s.x += s1.x + s2.x + s3.x + tiv.x;
        s.y += s1.y + s2.y + s3.y + tiv.y;
        s.z += s1.z + s2.z + s3.z + tiv.z;
        s.w += s1.w + s2.w + s3.w + tiv.w;
        rowf[t] = s;
    }
    __syncthreads();

    // scatter: src(h,w) = (h/10)*12 + (3w)/40 == n  <=>  h in [10y,10y+10),
    // w in [ceil(40x/3), ceil(40x/3 + 40/3)) where n = y*12+x.
    const int y = n / 12, x = n % 12;
    const int w_lo = (40 * x + 2) / 3;
    const int w_hi = (40 * x + 42) / 3;
    const float4 val = rowf[dq];
    const int h0 = 10 * y + 5 * half;
    for (int h = h0; h < h0 + 5; ++h) {
        float4* __restrict__ orow = out + (size_t)((b * H_OUT + h) * W_OUT) * 64 + dq;
        for (int w = w_lo + pg; w < w_hi; w += 4) {
            orow[(size_t)w * 64] = val;
        }
    }
}

extern "C" void kernel_launch(void* const* d_in, const int* in_sizes, int n_in,
                              void* d_out, int out_size, void* d_ws, size_t ws_size,
                              hipStream_t stream) {
    (void)in_sizes; (void)n_in; (void)out_size; (void)ws_size;
    const float* token_init  = (const float*)d_in[0];  // [4,144,256]
    const float* point_token = (const float*)d_in[1];  // [4,128,256]
    const float* nr_w1 = (const float*)d_in[2];
    const float* nr_b1 = (const float*)d_in[3];
    const float* nr_w2 = (const float*)d_in[4];
    const float* nr_b2 = (const float*)d_in[5];
    const float* na_w1 = (const float*)d_in[6];
    const float* na_b1 = (const float*)d_in[7];
    const float* na_w2 = (const float*)d_in[8];
    const float* na_b2 = (const float*)d_in[9];
    const float* tf_w1 = (const float*)d_in[10];
    const float* tf_b1 = (const float*)d_in[11];
    const float* tf_w2 = (const float*)d_in[12];
    const float* tf_b2 = (const float*)d_in[13];

    float* out = (float*)d_out;
    float* ws  = (float*)d_ws;
    float* nadjT = ws;                  //  73,728 f  [b*NP+p][n]
    float* attn  = nadjT + NROW * NP;   //  73,728 f
    float* tf    = attn + NROW * NP;    // 131,072 f
    float* ptT   = tf + B * NP * DIM;   // 131,072 f  [b][d][p]  (~1.6 MB total)

    k_t<<<128, 256, 0, stream>>>(point_token, ptT);
    k_mlp<<<288, 256, 0, stream>>>(token_init, ptT,
                                   nr_w1, nr_b1, nr_w2, nr_b2,
                                   na_w1, na_b1, na_w2, na_b2,
                                   nadjT, attn);
    k_fold<<<B * NP, 256, 0, stream>>>(nadjT, token_init,
                                       tf_w1, tf_b1, tf_w2, tf_b2, tf);
    k_final<<<NROW * 2, 256, 0, stream>>>(attn, tf, token_init, (float4*)out);
}